// Round 6
// baseline (3335.985 us; speedup 1.0000x reference)
//
#include <hip/hip_runtime.h>
#include <cmath>

// EMD approxmatch, B=16, N=M=2048, f32 — single persistent kernel.
// Factorized per-level update (nothing [N,M]-shaped): per level,
//   COL phase: A[m] = sum_n exp(l*d2)*ratioL[n];  rr = satr*min(satr/(satr*A+eps),1);
//              satr = max(satr - rr*A, 0)
//   ROW phase: s1 = sum_m e*rr; s2 = sum_m e*rr*dist;  satl=max(satl-rl*s1,0);
//              cost += rl*s2;  fused next-level ratioL via e2 = exp2(c_next*d2)
//              (e_this = e2^4 exactly, since levels scale by 4).
// Cross-block sync: per-batch 64-block barriers (deps never cross batches).
// satl + own ratioL live in lane0 registers for the whole solve.

#define NB 16
#define NPTS 2048
#define GRID (NB * 64)      // 64 blocks per batch, 32 rows + 32 cols each
#define TPB 256
#define EPS_F 1e-9f

__device__ __forceinline__ float fast_exp2(float x) { return __builtin_amdgcn_exp2f(x); }
__device__ __forceinline__ float fast_sqrt(float x) { return __builtin_amdgcn_sqrtf(x); }

// bar layout: bar[b*32] = per-batch phase counter (cacheline-spread); bar[512] = done
__global__ __launch_bounds__(256) void init_sync(int* __restrict__ bar,
                                                 float* __restrict__ costAcc) {
    for (int i = threadIdx.x; i < 513; i += 256) bar[i] = 0;
    if (threadIdx.x == 0) costAcc[0] = 0.0f;
}

__device__ __forceinline__ void batch_bar(int* cnt, int target) {
    __threadfence();                              // drain stores, wb L2 (cross-XCD)
    __syncthreads();
    if (threadIdx.x == 0) {
        atomicAdd(cnt, 1);                        // device-scope
        while (__hip_atomic_load(cnt, __ATOMIC_RELAXED, __HIP_MEMORY_SCOPE_AGENT) < target)
            __builtin_amdgcn_s_sleep(1);
        __threadfence();                          // invalidate L1/L2 before reads
    }
    __syncthreads();
}

__global__ __launch_bounds__(TPB, 4) void emd_all(const float* __restrict__ pred,
                                                  const float* __restrict__ gt,
                                                  float* __restrict__ ratioL,
                                                  float* __restrict__ ratioR,
                                                  float* __restrict__ satr,
                                                  float* __restrict__ costAcc,
                                                  int* __restrict__ bar,
                                                  float* __restrict__ out,
                                                  float c0) {
    __shared__ float Sx[NPTS], Sy[NPTS], Sz[NPTS], Sw[NPTS];   // 32768 B

    const int b = blockIdx.x >> 6;               // batch
    const int t = blockIdx.x & 63;               // tile within batch
    const int base = t * 32;
    const float* Pb = pred + (size_t)b * NPTS * 3;
    const float* Gb = gt   + (size_t)b * NPTS * 3;
    float* rlb = ratioL + b * NPTS;
    float* rrb = ratioR + b * NPTS;
    float* srb = satr   + b * NPTS;
    int* mybar = bar + b * 32;

    const int tid  = threadIdx.x;
    const int wave = tid >> 6, lane = tid & 63;
    const int own0 = base + wave * 8;            // 8 rows AND 8 cols per wave

    float myrl[8], mysl[8];                      // lane0-valid row state
    float costw = 0.0f;
    int phase = 0;

    // ---------- Phase R0: ratioL for level 0 (satl = satr = 1) ----------
    for (int i = tid; i < NPTS; i += TPB) {
        const float* g = Gb + i * 3;
        Sx[i] = g[0]; Sy[i] = g[1]; Sz[i] = g[2];
    }
    __syncthreads();
    {
        float px[8], py[8], pz[8], a[8];
        #pragma unroll
        for (int r = 0; r < 8; ++r) {
            const float* p = Pb + (size_t)(own0 + r) * 3;
            px[r] = p[0]; py[r] = p[1]; pz[r] = p[2]; a[r] = 0.0f;
        }
        #pragma unroll 2
        for (int i = lane; i < NPTS; i += 64) {
            float gx = Sx[i], gy = Sy[i], gz = Sz[i];
            #pragma unroll
            for (int r = 0; r < 8; ++r) {
                float dx = px[r] - gx, dy = py[r] - gy, dz = pz[r] - gz;
                float d2 = fmaf(dz, dz, fmaf(dy, dy, dx * dx));
                a[r] += fast_exp2(c0 * d2);
            }
        }
        #pragma unroll
        for (int o = 1; o < 64; o <<= 1) {
            #pragma unroll
            for (int r = 0; r < 8; ++r) a[r] += __shfl_xor(a[r], o);
        }
        if (lane == 0) {
            #pragma unroll
            for (int r = 0; r < 8; ++r) {
                mysl[r] = 1.0f;
                myrl[r] = 1.0f / (a[r] + EPS_F);
                rlb[own0 + r] = myrl[r];
            }
        }
    }
    ++phase; batch_bar(mybar, phase * 64);

    float cj = c0;                               // c_j = level_j * log2(e)
    for (int j = 0; j < 11; ++j) {
        // ================= COL phase =================
        if (j < 10) {
            for (int i = tid; i < NPTS; i += TPB) {
                const float* p = Pb + i * 3;
                Sx[i] = p[0]; Sy[i] = p[1]; Sz[i] = p[2]; Sw[i] = rlb[i];
            }
            __syncthreads();
            float gx[8], gy[8], gz[8], a[8];
            #pragma unroll
            for (int r = 0; r < 8; ++r) {
                const float* g = Gb + (size_t)(own0 + r) * 3;
                gx[r] = g[0]; gy[r] = g[1]; gz[r] = g[2]; a[r] = 0.0f;
            }
            #pragma unroll 2
            for (int i = lane; i < NPTS; i += 64) {
                float qx = Sx[i], qy = Sy[i], qz = Sz[i], rl = Sw[i];
                #pragma unroll
                for (int r = 0; r < 8; ++r) {
                    float dx = gx[r] - qx, dy = gy[r] - qy, dz = gz[r] - qz;
                    float d2 = fmaf(dz, dz, fmaf(dy, dy, dx * dx));
                    a[r] = fmaf(fast_exp2(cj * d2), rl, a[r]);
                }
            }
            #pragma unroll
            for (int o = 1; o < 64; o <<= 1) {
                #pragma unroll
                for (int r = 0; r < 8; ++r) a[r] += __shfl_xor(a[r], o);
            }
            if (lane == 0) {
                #pragma unroll
                for (int r = 0; r < 8; ++r) {
                    const int m = own0 + r;
                    const float sr = (j == 0) ? 1.0f : srb[m];
                    const float ss = sr * a[r] + EPS_F;
                    const float rr = sr * fminf(sr / ss, 1.0f);
                    rrb[m] = rr;
                    srb[m] = fmaxf(sr - rr * a[r], 0.0f);
                }
            }
        } else {
            // level 10 (exp==1): column-independent sum of ratioL
            float acc = 0.0f;
            for (int i = tid; i < NPTS; i += TPB) acc += rlb[i];
            __syncthreads();                     // Sx free for scratch
            Sx[tid] = acc;
            __syncthreads();
            for (int s = 128; s > 0; s >>= 1) {
                if (tid < s) Sx[tid] += Sx[tid + s];
                __syncthreads();
            }
            const float sumRL = Sx[0];
            if (tid < 32) {
                const int m = base + tid;
                const float sr = srb[m];
                const float ss = sr * sumRL + EPS_F;
                rrb[m] = sr * fminf(sr / ss, 1.0f);   // satr update dead
            }
        }
        ++phase; batch_bar(mybar, phase * 64);

        // ================= ROW phase =================
        for (int i = tid; i < NPTS; i += TPB) {
            const float* g = Gb + i * 3;
            Sx[i] = g[0]; Sy[i] = g[1]; Sz[i] = g[2]; Sw[i] = rrb[i];
        }
        __syncthreads();
        {
            float px[8], py[8], pz[8], s1[8], s2[8], an[8];
            #pragma unroll
            for (int r = 0; r < 8; ++r) {
                const float* p = Pb + (size_t)(own0 + r) * 3;
                px[r] = p[0]; py[r] = p[1]; pz[r] = p[2];
                s1[r] = 0.0f; s2[r] = 0.0f; an[r] = 0.0f;
            }
            float anall = 0.0f;
            if (j < 9) {
                const float cq = cj * 0.25f;     // = c_{j+1}
                #pragma unroll 2
                for (int i = lane; i < NPTS; i += 64) {
                    float gx = Sx[i], gy = Sy[i], gz = Sz[i], rr = Sw[i];
                    float nr = srb[i];           // L1-hot global
                    #pragma unroll
                    for (int r = 0; r < 8; ++r) {
                        float dx = px[r] - gx, dy = py[r] - gy, dz = pz[r] - gz;
                        float d2 = fmaf(dz, dz, fmaf(dy, dy, dx * dx));
                        float e2 = fast_exp2(cq * d2);
                        float e22 = e2 * e2;
                        an[r] = fmaf(e2, nr, an[r]);
                        float t_ = (e22 * e22) * rr;
                        s1[r] += t_;
                        s2[r] = fmaf(t_, fast_sqrt(d2), s2[r]);
                    }
                }
            } else if (j == 9) {
                #pragma unroll 2
                for (int i = lane; i < NPTS; i += 64) {
                    float gx = Sx[i], gy = Sy[i], gz = Sz[i], rr = Sw[i];
                    anall += srb[i];
                    #pragma unroll
                    for (int r = 0; r < 8; ++r) {
                        float dx = px[r] - gx, dy = py[r] - gy, dz = pz[r] - gz;
                        float d2 = fmaf(dz, dz, fmaf(dy, dy, dx * dx));
                        float t_ = fast_exp2(cj * d2) * rr;
                        s1[r] += t_;
                        s2[r] = fmaf(t_, fast_sqrt(d2), s2[r]);
                    }
                }
            } else {
                #pragma unroll 2
                for (int i = lane; i < NPTS; i += 64) {
                    float gx = Sx[i], gy = Sy[i], gz = Sz[i], rr = Sw[i];
                    #pragma unroll
                    for (int r = 0; r < 8; ++r) {
                        float dx = px[r] - gx, dy = py[r] - gy, dz = pz[r] - gz;
                        float d2 = fmaf(dz, dz, fmaf(dy, dy, dx * dx));
                        s2[r] = fmaf(rr, fast_sqrt(d2), s2[r]);
                    }
                }
            }
            #pragma unroll
            for (int o = 1; o < 64; o <<= 1) {
                #pragma unroll
                for (int r = 0; r < 8; ++r) {
                    s2[r] += __shfl_xor(s2[r], o);
                    if (j < 10) s1[r] += __shfl_xor(s1[r], o);
                    if (j < 9)  an[r] += __shfl_xor(an[r], o);
                }
                if (j == 9) anall += __shfl_xor(anall, o);
            }
            if (lane == 0) {
                #pragma unroll
                for (int r = 0; r < 8; ++r) {
                    const float rl = myrl[r];
                    costw += rl * s2[r];
                    if (j < 10) {
                        mysl[r] = fmaxf(mysl[r] - rl * s1[r], 0.0f);
                        const float den = (j < 9) ? an[r] : anall;
                        myrl[r] = mysl[r] / (den + EPS_F);
                        rlb[own0 + r] = myrl[r];
                    }
                }
            }
        }
        if (j < 10) { ++phase; batch_bar(mybar, phase * 64); }
        cj *= 0.25f;
    }

    // ---------- cost reduction & output ----------
    __syncthreads();
    if (lane == 0) Sx[wave] = costw;
    __syncthreads();
    if (tid == 0) {
        atomicAdd(costAcc, Sx[0] + Sx[1] + Sx[2] + Sx[3]);
        __threadfence();
        atomicAdd(bar + 512, 1);                  // done counter
    }
    if (blockIdx.x == 0 && tid == 0) {
        while (__hip_atomic_load(bar + 512, __ATOMIC_RELAXED, __HIP_MEMORY_SCOPE_AGENT) < GRID)
            __builtin_amdgcn_s_sleep(1);
        __threadfence();
        out[0] = *((volatile float*)costAcc) * (1.0f / (float)NPTS);
    }
}

extern "C" void kernel_launch(void* const* d_in, const int* in_sizes, int n_in,
                              void* d_out, int out_size, void* d_ws, size_t ws_size,
                              hipStream_t stream) {
    const float* pred = (const float*)d_in[0];
    const float* gt   = (const float*)d_in[1];
    float* out = (float*)d_out;

    float* wsf     = (float*)d_ws;
    float* ratioL  = wsf;                         // 32768
    float* ratioR  = wsf + NB * NPTS;             // 32768
    float* satrp   = wsf + 2 * NB * NPTS;         // 32768
    float* costAcc = wsf + 3 * NB * NPTS;         // 1
    int*   bar     = (int*)(wsf + 3 * NB * NPTS + 16);  // 513 ints, cacheline off costAcc

    const double LOG2E = 1.4426950408889634;
    const float c0 = (float)(-65536.0 * LOG2E);   // level_0 = -4^8

    init_sync<<<1, 256, 0, stream>>>(bar, costAcc);
    emd_all<<<GRID, TPB, 0, stream>>>(pred, gt, ratioL, ratioR, satrp,
                                      costAcc, bar, out, c0);
}

// Round 7
// 734.890 us; speedup vs baseline: 4.5394x; 4.5394x over previous
//
#include <hip/hip_runtime.h>
#include <cmath>

// EMD approxmatch, B=16, N=M=2048, f32 — persistent kernel, fence-free sync.
// Factorized per-level update (nothing [N,M]-shaped). Per level:
//   COL: A[m] = sum_n exp(l*d2)*ratioL[n]; rr = satr*min(satr/(satr*A+eps),1);
//        satr = max(satr - rr*A, 0)
//   ROW: s1 = sum_m e*rr; s2 = sum_m e*rr*dist; satl = max(satl - rl*s1, 0);
//        cost += rl*s2; fused next-level ratioL via e2 = exp2(c_next*d2),
//        e_this = e2^4 exactly (levels scale by 4).
// Cross-block data moves ONLY via relaxed agent-scope atomics (bypass stale
// caches per-access — no buffer_inv, coords stay L2-hot). Barriers are
// per-batch monotonic counters; __syncthreads' vmcnt(0) drain provides the
// release ordering (round 6's __threadfence buffer_inv caused 418MB HBM).

#define NB 16
#define NPTS 2048
#define BPB 64                   // blocks per batch (batch-local barriers)
#define GRID (NB * BPB)
#define TPB 256
#define EPS_F 1e-9f

#define AGENT __HIP_MEMORY_SCOPE_AGENT
#define RLX __ATOMIC_RELAXED

__device__ __forceinline__ float fast_exp2(float x) { return __builtin_amdgcn_exp2f(x); }
__device__ __forceinline__ float fast_sqrt(float x) { return __builtin_amdgcn_sqrtf(x); }

__device__ __forceinline__ float aloadf(const float* p) {
    return __hip_atomic_load(p, RLX, AGENT);
}
__device__ __forceinline__ void astoref(float* p, float v) {
    __hip_atomic_store(p, v, RLX, AGENT);
}
__device__ __forceinline__ unsigned long long aload64(const unsigned long long* p) {
    return __hip_atomic_load(p, RLX, AGENT);
}
__device__ __forceinline__ void astore64(unsigned long long* p, unsigned long long v) {
    __hip_atomic_store(p, v, RLX, AGENT);
}

__global__ __launch_bounds__(256) void init_sync(int* __restrict__ bar,
                                                 float* __restrict__ costAcc) {
    for (int i = threadIdx.x; i < 513; i += 256) bar[i] = 0;
    if (threadIdx.x == 0) costAcc[0] = 0.0f;
}

// No fences: __syncthreads drains vmcnt(0) (all prior atomic stores globally
// visible), then a relaxed increment + relaxed spin suffice.
__device__ __forceinline__ void batch_bar(int* cnt, int target) {
    __syncthreads();
    if (threadIdx.x == 0) {
        __hip_atomic_fetch_add(cnt, 1, RLX, AGENT);
        while (__hip_atomic_load(cnt, RLX, AGENT) < target)
            __builtin_amdgcn_s_sleep(2);
    }
    __syncthreads();
}

__global__ __launch_bounds__(TPB, 4) void emd_all(const float* __restrict__ pred,
                                                  const float* __restrict__ gt,
                                                  float* __restrict__ ratioL,
                                                  unsigned long long* __restrict__ rs,
                                                  float* __restrict__ costAcc,
                                                  int* __restrict__ bar,
                                                  float* __restrict__ out,
                                                  float c0) {
    __shared__ float4 S4[NPTS];              // {x,y,z,aux}  32768 B
    __shared__ float  Sn[NPTS];              // satr          8192 B  (40960 total)

    const int b = blockIdx.x >> 6;
    const int t = blockIdx.x & 63;
    const int base = t * 32;
    const float* Pb = pred + (size_t)b * NPTS * 3;
    const float* Gb = gt   + (size_t)b * NPTS * 3;
    float* rlb = ratioL + b * NPTS;
    unsigned long long* rsb = rs + b * NPTS;
    int* mybar = bar + b * 32;

    const int tid  = threadIdx.x;
    const int wave = tid >> 6, lane = tid & 63;
    const int own0 = base + wave * 8;        // 8 rows AND 8 cols per wave

    float myrl[8], mysl[8], mysr[8];         // lane0-valid per-row/col state
    float costw = 0.0f;
    int phase = 0;

    // ---------- Phase R0: ratioL for level 0 (satl = satr = 1) ----------
    for (int i = tid; i < NPTS; i += TPB) {
        const float* g = Gb + i * 3;
        S4[i] = make_float4(g[0], g[1], g[2], 0.0f);
    }
    __syncthreads();
    {
        float px[8], py[8], pz[8], a[8];
        #pragma unroll
        for (int r = 0; r < 8; ++r) {
            const float* p = Pb + (size_t)(own0 + r) * 3;
            px[r] = p[0]; py[r] = p[1]; pz[r] = p[2]; a[r] = 0.0f;
        }
        #pragma unroll 2
        for (int i = lane; i < NPTS; i += 64) {
            float4 g = S4[i];
            #pragma unroll
            for (int r = 0; r < 8; ++r) {
                float dx = px[r] - g.x, dy = py[r] - g.y, dz = pz[r] - g.z;
                float d2 = fmaf(dz, dz, fmaf(dy, dy, dx * dx));
                a[r] += fast_exp2(c0 * d2);
            }
        }
        #pragma unroll
        for (int o = 1; o < 64; o <<= 1) {
            #pragma unroll
            for (int r = 0; r < 8; ++r) a[r] += __shfl_xor(a[r], o);
        }
        if (lane == 0) {
            #pragma unroll
            for (int r = 0; r < 8; ++r) {
                mysl[r] = 1.0f; mysr[r] = 1.0f;
                myrl[r] = 1.0f / (a[r] + EPS_F);
                astoref(rlb + own0 + r, myrl[r]);
            }
        }
    }
    ++phase; batch_bar(mybar, phase * BPB);

    float cj = c0;                            // c_j = level_j * log2(e)
    for (int j = 0; j < 11; ++j) {
        // ================= COL phase =================
        if (j < 10) {
            for (int i = tid; i < NPTS; i += TPB) {
                const float* p = Pb + i * 3;
                S4[i] = make_float4(p[0], p[1], p[2], aloadf(rlb + i));
            }
            __syncthreads();
            float gx[8], gy[8], gz[8], a[8];
            #pragma unroll
            for (int r = 0; r < 8; ++r) {
                const float* g = Gb + (size_t)(own0 + r) * 3;
                gx[r] = g[0]; gy[r] = g[1]; gz[r] = g[2]; a[r] = 0.0f;
            }
            #pragma unroll 2
            for (int i = lane; i < NPTS; i += 64) {
                float4 q = S4[i];
                #pragma unroll
                for (int r = 0; r < 8; ++r) {
                    float dx = gx[r] - q.x, dy = gy[r] - q.y, dz = gz[r] - q.z;
                    float d2 = fmaf(dz, dz, fmaf(dy, dy, dx * dx));
                    a[r] = fmaf(fast_exp2(cj * d2), q.w, a[r]);
                }
            }
            #pragma unroll
            for (int o = 1; o < 64; o <<= 1) {
                #pragma unroll
                for (int r = 0; r < 8; ++r) a[r] += __shfl_xor(a[r], o);
            }
            if (lane == 0) {
                #pragma unroll
                for (int r = 0; r < 8; ++r) {
                    const float sr = mysr[r];
                    const float ss = sr * a[r] + EPS_F;
                    const float rr = sr * fminf(sr / ss, 1.0f);
                    const float srn = fmaxf(sr - rr * a[r], 0.0f);
                    mysr[r] = srn;
                    unsigned long long u =
                        ((unsigned long long)__float_as_uint(srn) << 32) | __float_as_uint(rr);
                    astore64(rsb + own0 + r, u);
                }
            }
        } else {
            // level 10 (exp==1): column-independent sum of ratioL
            float acc = 0.0f;
            for (int i = tid; i < NPTS; i += TPB) acc += aloadf(rlb + i);
            __syncthreads();
            float* sc = (float*)S4;
            sc[tid] = acc;
            __syncthreads();
            for (int s = 128; s > 0; s >>= 1) {
                if (tid < s) sc[tid] += sc[tid + s];
                __syncthreads();
            }
            const float sumRL = sc[0];
            __syncthreads();
            if (lane == 0) {
                #pragma unroll
                for (int r = 0; r < 8; ++r) {
                    const float sr = mysr[r];
                    const float ss = sr * sumRL + EPS_F;
                    const float rr = sr * fminf(sr / ss, 1.0f);
                    unsigned long long u =
                        ((unsigned long long)__float_as_uint(sr) << 32) | __float_as_uint(rr);
                    astore64(rsb + own0 + r, u);
                }
            }
        }
        ++phase; batch_bar(mybar, phase * BPB);

        // ================= ROW phase =================
        for (int i = tid; i < NPTS; i += TPB) {
            const float* g = Gb + i * 3;
            unsigned long long u = aload64(rsb + i);
            S4[i] = make_float4(g[0], g[1], g[2],
                                __uint_as_float((unsigned)(u & 0xffffffffu)));
            if (j <= 9) Sn[i] = __uint_as_float((unsigned)(u >> 32));
        }
        __syncthreads();
        {
            float px[8], py[8], pz[8], s1[8], s2[8], an[8];
            #pragma unroll
            for (int r = 0; r < 8; ++r) {
                const float* p = Pb + (size_t)(own0 + r) * 3;
                px[r] = p[0]; py[r] = p[1]; pz[r] = p[2];
                s1[r] = 0.0f; s2[r] = 0.0f; an[r] = 0.0f;
            }
            float anall = 0.0f;
            if (j < 9) {
                const float cq = cj * 0.25f;  // = c_{j+1}
                #pragma unroll 2
                for (int i = lane; i < NPTS; i += 64) {
                    float4 g = S4[i];
                    float nr = Sn[i];
                    #pragma unroll
                    for (int r = 0; r < 8; ++r) {
                        float dx = px[r] - g.x, dy = py[r] - g.y, dz = pz[r] - g.z;
                        float d2 = fmaf(dz, dz, fmaf(dy, dy, dx * dx));
                        float e2 = fast_exp2(cq * d2);
                        float e22 = e2 * e2;
                        an[r] = fmaf(e2, nr, an[r]);
                        float t_ = (e22 * e22) * g.w;
                        s1[r] += t_;
                        s2[r] = fmaf(t_, fast_sqrt(d2), s2[r]);
                    }
                }
            } else if (j == 9) {
                #pragma unroll 2
                for (int i = lane; i < NPTS; i += 64) {
                    float4 g = S4[i];
                    anall += Sn[i];
                    #pragma unroll
                    for (int r = 0; r < 8; ++r) {
                        float dx = px[r] - g.x, dy = py[r] - g.y, dz = pz[r] - g.z;
                        float d2 = fmaf(dz, dz, fmaf(dy, dy, dx * dx));
                        float t_ = fast_exp2(cj * d2) * g.w;
                        s1[r] += t_;
                        s2[r] = fmaf(t_, fast_sqrt(d2), s2[r]);
                    }
                }
            } else {
                #pragma unroll 2
                for (int i = lane; i < NPTS; i += 64) {
                    float4 g = S4[i];
                    #pragma unroll
                    for (int r = 0; r < 8; ++r) {
                        float dx = px[r] - g.x, dy = py[r] - g.y, dz = pz[r] - g.z;
                        float d2 = fmaf(dz, dz, fmaf(dy, dy, dx * dx));
                        s2[r] = fmaf(g.w, fast_sqrt(d2), s2[r]);
                    }
                }
            }
            #pragma unroll
            for (int o = 1; o < 64; o <<= 1) {
                #pragma unroll
                for (int r = 0; r < 8; ++r) {
                    s2[r] += __shfl_xor(s2[r], o);
                    if (j < 10) s1[r] += __shfl_xor(s1[r], o);
                    if (j < 9)  an[r] += __shfl_xor(an[r], o);
                }
                if (j == 9) anall += __shfl_xor(anall, o);
            }
            if (lane == 0) {
                #pragma unroll
                for (int r = 0; r < 8; ++r) {
                    const float rl = myrl[r];
                    costw += rl * s2[r];
                    if (j < 10) {
                        mysl[r] = fmaxf(mysl[r] - rl * s1[r], 0.0f);
                        const float den = (j < 9) ? an[r] : anall;
                        myrl[r] = mysl[r] / (den + EPS_F);
                        astoref(rlb + own0 + r, myrl[r]);
                    }
                }
            }
        }
        if (j < 10) { ++phase; batch_bar(mybar, phase * BPB); }
        cj *= 0.25f;
    }

    // ---------- cost reduction & output ----------
    __syncthreads();
    float* sc = (float*)S4;
    if (lane == 0) sc[wave] = costw;
    __syncthreads();
    if (tid == 0) {
        __hip_atomic_fetch_add(costAcc, sc[0] + sc[1] + sc[2] + sc[3], RLX, AGENT);
        // atomic has landed at coherence point before done-increment issues:
        __builtin_amdgcn_s_waitcnt(0);        // vmcnt(0) lgkmcnt(0)
        __hip_atomic_fetch_add(bar + 512, 1, RLX, AGENT);
    }
    if (blockIdx.x == 0 && tid == 0) {
        while (__hip_atomic_load(bar + 512, RLX, AGENT) < GRID)
            __builtin_amdgcn_s_sleep(2);
        out[0] = __hip_atomic_load(costAcc, RLX, AGENT) * (1.0f / (float)NPTS);
    }
}

extern "C" void kernel_launch(void* const* d_in, const int* in_sizes, int n_in,
                              void* d_out, int out_size, void* d_ws, size_t ws_size,
                              hipStream_t stream) {
    const float* pred = (const float*)d_in[0];
    const float* gt   = (const float*)d_in[1];
    float* out = (float*)d_out;

    float* wsf = (float*)d_ws;
    float* ratioL = wsf;                                             // 32768 f32
    unsigned long long* rs = (unsigned long long*)(wsf + NB * NPTS); // 32768 u64 (8B-aligned)
    float* costAcc = (float*)(rs + NB * NPTS);
    int*   bar     = (int*)(costAcc + 16);                           // 513 ints

    const double LOG2E = 1.4426950408889634;
    const float c0 = (float)(-65536.0 * LOG2E);   // level_0 = -4^8

    init_sync<<<1, 256, 0, stream>>>(bar, costAcc);
    emd_all<<<GRID, TPB, 0, stream>>>(pred, gt, ratioL, rs, costAcc, bar, out, c0);
}

// Round 8
// 686.503 us; speedup vs baseline: 4.8594x; 1.0705x over previous
//
#include <hip/hip_runtime.h>
#include <cmath>

// EMD approxmatch, B=16, N=M=2048, f32 — persistent kernel, fence-free sync.
// Factorized per-level update (nothing [N,M]-shaped). Per level:
//   COL: A[m] = sum_n exp(l*d2)*ratioL[n]; rr = satr*min(satr/(satr*A+eps),1);
//        satr = max(satr - rr*A, 0)
//   ROW: s1 = sum_m e*rr; s2 = sum_m e*rr*dist; satl = max(satl - rl*s1, 0);
//        cost += rl*s2; fused next-level ratioL via e2 = exp2(c_next*d2),
//        e_this = e2^4 exactly (levels scale by 4).
// Cross-block dynamic data via relaxed agent-scope atomics (cache-bypass, no
// buffer_inv). Staging batched (loads->regs->LDS, one latency exposure);
// static coords staged pre-barrier with cached loads. Packed f32 (v_pk_*)
// over the i-dimension; per-row/col state distributed on lanes 0..7.

#define NB 16
#define NPTS 2048
#define NH 1024                  // v2f pairs
#define BPB 64                   // blocks per batch
#define GRID (NB * BPB)
#define TPB 256
#define EPS_F 1e-9f

#define AGENT __HIP_MEMORY_SCOPE_AGENT
#define RLX __ATOMIC_RELAXED

typedef float v2f __attribute__((ext_vector_type(2)));

__device__ __forceinline__ float fast_exp2(float x) { return __builtin_amdgcn_exp2f(x); }
__device__ __forceinline__ float fast_sqrt(float x) { return __builtin_amdgcn_sqrtf(x); }
__device__ __forceinline__ v2f v2(float s) { v2f r; r.x = s; r.y = s; return r; }
__device__ __forceinline__ v2f vfma(v2f a, v2f b, v2f c) { return __builtin_elementwise_fma(a, b, c); }
__device__ __forceinline__ v2f vexp2(v2f a) { v2f r; r.x = fast_exp2(a.x); r.y = fast_exp2(a.y); return r; }
__device__ __forceinline__ v2f vsqrt(v2f a) { v2f r; r.x = fast_sqrt(a.x); r.y = fast_sqrt(a.y); return r; }

__device__ __forceinline__ float aloadf(const float* p) { return __hip_atomic_load(p, RLX, AGENT); }
__device__ __forceinline__ void astoref(float* p, float v) { __hip_atomic_store(p, v, RLX, AGENT); }
__device__ __forceinline__ unsigned long long aload64(const unsigned long long* p) { return __hip_atomic_load(p, RLX, AGENT); }
__device__ __forceinline__ void astore64(unsigned long long* p, unsigned long long v) { __hip_atomic_store(p, v, RLX, AGENT); }

// 8-way select without runtime array indexing (7 cndmask)
__device__ __forceinline__ float sel8(float a0, float a1, float a2, float a3,
                                      float a4, float a5, float a6, float a7, int k) {
    float x = a0;
    x = (k == 1) ? a1 : x; x = (k == 2) ? a2 : x; x = (k == 3) ? a3 : x;
    x = (k == 4) ? a4 : x; x = (k == 5) ? a5 : x; x = (k == 6) ? a6 : x;
    x = (k == 7) ? a7 : x;
    return x;
}
#define SEL8(A, k) sel8(A[0], A[1], A[2], A[3], A[4], A[5], A[6], A[7], k)

__global__ __launch_bounds__(256) void init_sync(int* __restrict__ bar,
                                                 float* __restrict__ costAcc) {
    for (int i = threadIdx.x; i < 513; i += 256) bar[i] = 0;
    if (threadIdx.x == 0) costAcc[0] = 0.0f;
}

// __syncthreads drains vmcnt (all prior stores globally visible for sc-stores),
// then relaxed inc + relaxed spin.
__device__ __forceinline__ void batch_bar(int* cnt, int target) {
    __syncthreads();
    if (threadIdx.x == 0) {
        __hip_atomic_fetch_add(cnt, 1, RLX, AGENT);
        while (__hip_atomic_load(cnt, RLX, AGENT) < target)
            __builtin_amdgcn_s_sleep(2);
    }
    __syncthreads();
}

__global__ __launch_bounds__(TPB, 4) void emd_all(const float* __restrict__ pred,
                                                  const float* __restrict__ gt,
                                                  float* __restrict__ ratioL,
                                                  unsigned long long* __restrict__ rs,
                                                  float* __restrict__ costAcc,
                                                  int* __restrict__ bar,
                                                  float* __restrict__ out,
                                                  float c0) {
    // SoA v2f tiles over point pairs: 5 * 8 KB = 40960 B (160 KiB / 4)
    __shared__ v2f Sx[NH], Sy[NH], Sz[NH], Sw[NH], Sn[NH];

    const int b = blockIdx.x >> 6;
    const int t = blockIdx.x & 63;
    const int base = t * 32;
    const float* Pb = pred + (size_t)b * NPTS * 3;
    const float* Gb = gt   + (size_t)b * NPTS * 3;
    float* rlb = ratioL + b * NPTS;
    unsigned long long* rsb = rs + b * NPTS;
    int* mybar = bar + b * 32;

    const int tid  = threadIdx.x;
    const int wave = tid >> 6, lane = tid & 63;
    const int own0 = base + wave * 8;        // 8 rows AND 8 cols per wave
    const int lr = lane & 7;                 // this lane's owned row/col (lanes 0..7)

    float myrl = 0.0f, mysl = 1.0f, mysr = 1.0f;   // state on lanes 0..7
    float costw = 0.0f;
    int phase = 0;

    // ---- staging helpers (each thread owns 8 consecutive points) ----
    // coords: 6 float4 cached loads -> SoA v2f
    #define STAGE_COORDS(Cb)                                                    \
    {                                                                           \
        const float4* C4 = (const float4*)(Cb);                                 \
        float4 f0 = C4[6 * tid + 0], f1 = C4[6 * tid + 1], f2 = C4[6 * tid + 2];\
        float4 f3 = C4[6 * tid + 3], f4 = C4[6 * tid + 4], f5 = C4[6 * tid + 5];\
        float fl[24] = {f0.x, f0.y, f0.z, f0.w, f1.x, f1.y, f1.z, f1.w,         \
                        f2.x, f2.y, f2.z, f2.w, f3.x, f3.y, f3.z, f3.w,         \
                        f4.x, f4.y, f4.z, f4.w, f5.x, f5.y, f5.z, f5.w};        \
        _Pragma("unroll")                                                       \
        for (int jj = 0; jj < 4; ++jj) {                                        \
            Sx[4 * tid + jj] = (v2f){fl[6 * jj + 0], fl[6 * jj + 3]};           \
            Sy[4 * tid + jj] = (v2f){fl[6 * jj + 1], fl[6 * jj + 4]};           \
            Sz[4 * tid + jj] = (v2f){fl[6 * jj + 2], fl[6 * jj + 5]};           \
        }                                                                       \
    }
    // dynamic rl -> Sw: 8 batched bypass loads, then LDS
    #define STAGE_RL()                                                          \
    {                                                                           \
        float u[8];                                                             \
        _Pragma("unroll")                                                       \
        for (int j_ = 0; j_ < 8; ++j_) u[j_] = aloadf(rlb + 8 * tid + j_);      \
        _Pragma("unroll")                                                       \
        for (int jj = 0; jj < 4; ++jj)                                          \
            Sw[4 * tid + jj] = (v2f){u[2 * jj], u[2 * jj + 1]};                 \
    }
    // dynamic rs -> Sw (rr = lo), Sn (satr = hi)
    #define STAGE_RS()                                                          \
    {                                                                           \
        unsigned long long u[8];                                                \
        _Pragma("unroll")                                                       \
        for (int j_ = 0; j_ < 8; ++j_) u[j_] = aload64(rsb + 8 * tid + j_);     \
        _Pragma("unroll")                                                       \
        for (int jj = 0; jj < 4; ++jj) {                                        \
            Sw[4 * tid + jj] = (v2f){                                           \
                __uint_as_float((unsigned)(u[2 * jj] & 0xffffffffu)),           \
                __uint_as_float((unsigned)(u[2 * jj + 1] & 0xffffffffu))};      \
            Sn[4 * tid + jj] = (v2f){                                           \
                __uint_as_float((unsigned)(u[2 * jj] >> 32)),                   \
                __uint_as_float((unsigned)(u[2 * jj + 1] >> 32))};              \
        }                                                                       \
    }

    // ---------- Phase R0: ratioL for level 0 (satl = satr = 1) ----------
    STAGE_COORDS(Gb);
    __syncthreads();
    {
        float px[8], py[8], pz[8];
        v2f a[8];
        #pragma unroll
        for (int r = 0; r < 8; ++r) {
            const float* p = Pb + (size_t)(own0 + r) * 3;
            px[r] = p[0]; py[r] = p[1]; pz[r] = p[2]; a[r] = v2(0.0f);
        }
        for (int i = lane; i < NH; i += 64) {
            v2f gx = Sx[i], gy = Sy[i], gz = Sz[i];
            #pragma unroll
            for (int r = 0; r < 8; ++r) {
                v2f dx = v2(px[r]) - gx, dy = v2(py[r]) - gy, dz = v2(pz[r]) - gz;
                v2f d2 = vfma(dz, dz, vfma(dy, dy, dx * dx));
                a[r] += vexp2(d2 * v2(c0));
            }
        }
        float as[8];
        #pragma unroll
        for (int r = 0; r < 8; ++r) as[r] = a[r].x + a[r].y;
        #pragma unroll
        for (int o = 1; o < 64; o <<= 1) {
            #pragma unroll
            for (int r = 0; r < 8; ++r) as[r] += __shfl_xor(as[r], o);
        }
        if (lane < 8) {
            myrl = 1.0f / (SEL8(as, lr) + EPS_F);
            astoref(rlb + own0 + lr, myrl);
        }
    }
    __syncthreads();
    STAGE_COORDS(Pb);                          // pred coords for COL, pre-barrier
    ++phase; batch_bar(mybar, phase * BPB);

    float cj = c0;                             // c_j = level_j * log2(e)
    for (int j = 0; j < 11; ++j) {
        // ================= COL phase =================
        if (j < 10) {
            STAGE_RL();
            __syncthreads();
            float gx[8], gy[8], gz[8];
            v2f a[8];
            #pragma unroll
            for (int r = 0; r < 8; ++r) {
                const float* g = Gb + (size_t)(own0 + r) * 3;
                gx[r] = g[0]; gy[r] = g[1]; gz[r] = g[2]; a[r] = v2(0.0f);
            }
            for (int i = lane; i < NH; i += 64) {
                v2f qx = Sx[i], qy = Sy[i], qz = Sz[i], rl = Sw[i];
                #pragma unroll
                for (int r = 0; r < 8; ++r) {
                    v2f dx = v2(gx[r]) - qx, dy = v2(gy[r]) - qy, dz = v2(gz[r]) - qz;
                    v2f d2 = vfma(dz, dz, vfma(dy, dy, dx * dx));
                    a[r] = vfma(vexp2(d2 * v2(cj)), rl, a[r]);
                }
            }
            float as[8];
            #pragma unroll
            for (int r = 0; r < 8; ++r) as[r] = a[r].x + a[r].y;
            #pragma unroll
            for (int o = 1; o < 64; o <<= 1) {
                #pragma unroll
                for (int r = 0; r < 8; ++r) as[r] += __shfl_xor(as[r], o);
            }
            if (lane < 8) {
                const float A = SEL8(as, lr);
                const float sr = mysr;
                const float ss = fmaf(sr, A, EPS_F);
                const float rr = sr * fminf(sr / ss, 1.0f);
                const float srn = fmaxf(fmaf(-rr, A, sr), 0.0f);
                mysr = srn;
                unsigned long long u =
                    ((unsigned long long)__float_as_uint(srn) << 32) | __float_as_uint(rr);
                astore64(rsb + own0 + lr, u);
            }
        } else {
            // level 10 (exp==1): column-independent sum of ratioL
            float acc = 0.0f;
            {
                float u[8];
                #pragma unroll
                for (int j_ = 0; j_ < 8; ++j_) u[j_] = aloadf(rlb + 8 * tid + j_);
                #pragma unroll
                for (int j_ = 0; j_ < 8; ++j_) acc += u[j_];
            }
            __syncthreads();
            float* scr = (float*)Sx;
            scr[tid] = acc;
            __syncthreads();
            for (int s = 128; s > 0; s >>= 1) {
                if (tid < s) scr[tid] += scr[tid + s];
                __syncthreads();
            }
            const float sumRL = scr[0];
            __syncthreads();
            if (lane < 8) {
                const float sr = mysr;
                const float ss = fmaf(sr, sumRL, EPS_F);
                const float rr = sr * fminf(sr / ss, 1.0f);
                unsigned long long u =
                    ((unsigned long long)__float_as_uint(sr) << 32) | __float_as_uint(rr);
                astore64(rsb + own0 + lr, u);
            }
        }
        __syncthreads();
        STAGE_COORDS(Gb);                      // gt coords for ROW, pre-barrier
        ++phase; batch_bar(mybar, phase * BPB);

        // ================= ROW phase =================
        STAGE_RS();
        __syncthreads();
        {
            float px[8], py[8], pz[8];
            v2f s1[8], s2[8], an[8], anall = v2(0.0f);
            #pragma unroll
            for (int r = 0; r < 8; ++r) {
                const float* p = Pb + (size_t)(own0 + r) * 3;
                px[r] = p[0]; py[r] = p[1]; pz[r] = p[2];
                s1[r] = v2(0.0f); s2[r] = v2(0.0f); an[r] = v2(0.0f);
            }
            if (j < 9) {
                const float cq = cj * 0.25f;   // = c_{j+1}
                for (int i = lane; i < NH; i += 64) {
                    v2f gx = Sx[i], gy = Sy[i], gz = Sz[i], rr = Sw[i], nr = Sn[i];
                    #pragma unroll
                    for (int r = 0; r < 8; ++r) {
                        v2f dx = v2(px[r]) - gx, dy = v2(py[r]) - gy, dz = v2(pz[r]) - gz;
                        v2f d2 = vfma(dz, dz, vfma(dy, dy, dx * dx));
                        v2f e2 = vexp2(d2 * v2(cq));
                        v2f e22 = e2 * e2;
                        an[r] = vfma(e2, nr, an[r]);
                        v2f t_ = (e22 * e22) * rr;
                        s1[r] += t_;
                        s2[r] = vfma(t_, vsqrt(d2), s2[r]);
                    }
                }
            } else if (j == 9) {
                for (int i = lane; i < NH; i += 64) {
                    v2f gx = Sx[i], gy = Sy[i], gz = Sz[i], rr = Sw[i];
                    anall += Sn[i];
                    #pragma unroll
                    for (int r = 0; r < 8; ++r) {
                        v2f dx = v2(px[r]) - gx, dy = v2(py[r]) - gy, dz = v2(pz[r]) - gz;
                        v2f d2 = vfma(dz, dz, vfma(dy, dy, dx * dx));
                        v2f t_ = vexp2(d2 * v2(cj)) * rr;
                        s1[r] += t_;
                        s2[r] = vfma(t_, vsqrt(d2), s2[r]);
                    }
                }
            } else {
                for (int i = lane; i < NH; i += 64) {
                    v2f gx = Sx[i], gy = Sy[i], gz = Sz[i], rr = Sw[i];
                    #pragma unroll
                    for (int r = 0; r < 8; ++r) {
                        v2f dx = v2(px[r]) - gx, dy = v2(py[r]) - gy, dz = v2(pz[r]) - gz;
                        v2f d2 = vfma(dz, dz, vfma(dy, dy, dx * dx));
                        s2[r] = vfma(rr, vsqrt(d2), s2[r]);
                    }
                }
            }
            float S1[8], S2[8], AN[8], ana = anall.x + anall.y;
            #pragma unroll
            for (int r = 0; r < 8; ++r) {
                S1[r] = s1[r].x + s1[r].y;
                S2[r] = s2[r].x + s2[r].y;
                AN[r] = an[r].x + an[r].y;
            }
            #pragma unroll
            for (int o = 1; o < 64; o <<= 1) {
                #pragma unroll
                for (int r = 0; r < 8; ++r) {
                    S2[r] += __shfl_xor(S2[r], o);
                    if (j < 10) S1[r] += __shfl_xor(S1[r], o);
                    if (j < 9)  AN[r] += __shfl_xor(AN[r], o);
                }
                if (j == 9) ana += __shfl_xor(ana, o);
            }
            float contrib = 0.0f;
            if (lane < 8) {
                const float rl = myrl;
                contrib = rl * SEL8(S2, lr);
                if (j < 10) {
                    mysl = fmaxf(fmaf(-rl, SEL8(S1, lr), mysl), 0.0f);
                    const float den = (j < 9) ? SEL8(AN, lr) : ana;
                    myrl = mysl / (den + EPS_F);
                    astoref(rlb + own0 + lr, myrl);
                }
            }
            contrib += __shfl_xor(contrib, 1);
            contrib += __shfl_xor(contrib, 2);
            contrib += __shfl_xor(contrib, 4);
            costw += contrib;                  // identical on lanes 0..7, 0 elsewhere
        }
        if (j < 10) {
            __syncthreads();
            STAGE_COORDS(Pb);                  // pred coords for next COL
            ++phase; batch_bar(mybar, phase * BPB);
        }
        cj *= 0.25f;
    }

    // ---------- cost reduction & output ----------
    __syncthreads();
    float* scr = (float*)Sx;
    if (lane == 0) scr[wave] = costw;
    __syncthreads();
    if (tid == 0) {
        __hip_atomic_fetch_add(costAcc, scr[0] + scr[1] + scr[2] + scr[3], RLX, AGENT);
        __builtin_amdgcn_s_waitcnt(0);
        __hip_atomic_fetch_add(bar + 512, 1, RLX, AGENT);
    }
    if (blockIdx.x == 0 && tid == 0) {
        while (__hip_atomic_load(bar + 512, RLX, AGENT) < GRID)
            __builtin_amdgcn_s_sleep(2);
        out[0] = __hip_atomic_load(costAcc, RLX, AGENT) * (1.0f / (float)NPTS);
    }
}

extern "C" void kernel_launch(void* const* d_in, const int* in_sizes, int n_in,
                              void* d_out, int out_size, void* d_ws, size_t ws_size,
                              hipStream_t stream) {
    const float* pred = (const float*)d_in[0];
    const float* gt   = (const float*)d_in[1];
    float* out = (float*)d_out;

    float* wsf = (float*)d_ws;
    float* ratioL = wsf;                                             // 32768 f32
    unsigned long long* rs = (unsigned long long*)(wsf + NB * NPTS); // 32768 u64
    float* costAcc = (float*)(rs + NB * NPTS);
    int*   bar     = (int*)(costAcc + 16);                           // 513 ints

    const double LOG2E = 1.4426950408889634;
    const float c0 = (float)(-65536.0 * LOG2E);   // level_0 = -4^8

    init_sync<<<1, 256, 0, stream>>>(bar, costAcc);
    emd_all<<<GRID, TPB, 0, stream>>>(pred, gt, ratioL, rs, costAcc, bar, out, c0);
}

// Round 9
// 629.112 us; speedup vs baseline: 5.3027x; 1.0912x over previous
//
#include <hip/hip_runtime.h>
#include <cmath>

// EMD approxmatch, B=16, N=M=2048, f32. Multi-launch (kernel boundary = sync,
// plain cached loads — no atomics). Factorized per-level update:
//   COL j: A[m] = sum_n e_j*ratioL[n]; rr = satr*min(satr/(satr*A+eps),1);
//          satr = max(satr - rr*A, 0)
//   ROW j: s1 = sum_m e_j*rr; s2 = sum_m e_j*rr*dist; satl=max(satl-rl*s1,0);
//          cost += rl*s2; fused next ratioL via e2 = exp2(c_{j+1}*d2),
//          e_j = e2^4 exactly (levels scale by 4).
// This round: 32KB LDS (5 blocks/CU), conflict-free SoA-v2f staging
// (stride-256, float2 loads), dot-form d2, packed-f32 math (v2f).

#define NB 16
#define NPTS 2048
#define NH 1024                 // v2f pair count
#define TPB 256
#define EPS_F 1e-9f

typedef float v2f __attribute__((ext_vector_type(2)));

__device__ __forceinline__ float fast_exp2(float x) { return __builtin_amdgcn_exp2f(x); }
__device__ __forceinline__ float fast_sqrt(float x) { return __builtin_amdgcn_sqrtf(x); }
__device__ __forceinline__ v2f v2(float s) { v2f r; r.x = s; r.y = s; return r; }
__device__ __forceinline__ v2f vfma(v2f a, v2f b, v2f c) { return __builtin_elementwise_fma(a, b, c); }
__device__ __forceinline__ v2f vmax0(v2f a) { return __builtin_elementwise_max(a, v2(0.0f)); }
__device__ __forceinline__ v2f vexp2(v2f a) { v2f r; r.x = fast_exp2(a.x); r.y = fast_exp2(a.y); return r; }
__device__ __forceinline__ v2f vsqrt(v2f a) { v2f r; r.x = fast_sqrt(a.x); r.y = fast_sqrt(a.y); return r; }

// 4-way select without runtime indexing (3 cndmask)
__device__ __forceinline__ float sel4(float a0, float a1, float a2, float a3, int k) {
    float x = a0;
    x = (k == 1) ? a1 : x; x = (k == 2) ? a2 : x; x = (k == 3) ? a3 : x;
    return x;
}
#define SEL4(A, k) sel4(A[0], A[1], A[2], A[3], k)

// ---- staging: SoA v2f tiles, thread t owns v2f-indices t, t+256, ... ----
// coords: 3 float2 loads (8B-aligned at 24B stride); aux: 1 float2 load.
#define STAGE_CW(Cb, Wb)                                                   \
    for (int i = tid; i < NH; i += TPB) {                                  \
        const float2* c2 = (const float2*)(Cb) + 3 * i;                    \
        float2 A_ = c2[0], B_ = c2[1], C_ = c2[2];                         \
        Sx[i] = (v2f){A_.x, B_.y};                                         \
        Sy[i] = (v2f){A_.y, C_.x};                                         \
        Sz[i] = (v2f){B_.x, C_.y};                                         \
        float2 w_ = *((const float2*)(Wb) + i);                            \
        Sw[i] = (v2f){w_.x, w_.y};                                         \
    }
#define STAGE_C(Cb)                                                        \
    for (int i = tid; i < NH; i += TPB) {                                  \
        const float2* c2 = (const float2*)(Cb) + 3 * i;                    \
        float2 A_ = c2[0], B_ = c2[1], C_ = c2[2];                         \
        Sx[i] = (v2f){A_.x, B_.y};                                         \
        Sy[i] = (v2f){A_.y, C_.x};                                         \
        Sz[i] = (v2f){B_.x, C_.y};                                         \
    }

// ratioL[n] = 1 / (sum_m exp2(c0*d2) + eps)   (satl = satr = 1 at level 0)
// Also zeroes costAcc (runs before any row_finish).
__global__ __launch_bounds__(TPB, 5) void row_start(const float* __restrict__ pred,
                                                    const float* __restrict__ gt,
                                                    float* __restrict__ ratioL,
                                                    float* __restrict__ costAcc,
                                                    float c0) {
    __shared__ v2f Sx[NH], Sy[NH], Sz[NH], Sw[NH];   // 32768 B
    const int b = blockIdx.x >> 7;                    // 128 blocks/batch, 16 rows
    const int base = (blockIdx.x & 127) * 16;
    const int tid = threadIdx.x, wave = tid >> 6, lane = tid & 63;
    if (blockIdx.x == 0 && tid == 0) costAcc[0] = 0.0f;
    const float* Gb = gt + (size_t)b * NPTS * 3;
    STAGE_C(Gb);
    __syncthreads();
    const int own0 = base + wave * 4;
    const float* p0 = pred + ((size_t)b * NPTS + own0) * 3;
    float nx[4], ny[4], nz[4], p2[4];
    v2f a[4];
    #pragma unroll
    for (int r = 0; r < 4; ++r) {
        float px = p0[r * 3], py = p0[r * 3 + 1], pz = p0[r * 3 + 2];
        nx[r] = -2.0f * px; ny[r] = -2.0f * py; nz[r] = -2.0f * pz;
        p2[r] = px * px + py * py + pz * pz;
        a[r] = v2(0.0f);
    }
    for (int i = lane; i < NH; i += 64) {
        v2f gx = Sx[i], gy = Sy[i], gz = Sz[i];
        v2f g2 = vfma(gx, gx, vfma(gy, gy, gz * gz));
        #pragma unroll
        for (int r = 0; r < 4; ++r) {
            v2f d2 = vmax0(vfma(v2(nx[r]), gx, vfma(v2(ny[r]), gy,
                           vfma(v2(nz[r]), gz, g2 + v2(p2[r])))));
            a[r] += vexp2(d2 * v2(c0));
        }
    }
    float as[4];
    #pragma unroll
    for (int r = 0; r < 4; ++r) as[r] = a[r].x + a[r].y;
    #pragma unroll
    for (int o = 1; o < 64; o <<= 1) {
        #pragma unroll
        for (int r = 0; r < 4; ++r) as[r] += __shfl_xor(as[r], o);
    }
    if (lane < 4)
        ratioL[b * NPTS + own0 + lane] = 1.0f / (SEL4(as, lane) + EPS_F);
}

// A[m] = sum_n exp2(c*d2)*ratioL[n]; rr = satr*min(satr/(satr*A+eps),1);
// satr = max(satr - rr*A, 0).  FIRST: satr = 1.
template <bool FIRST>
__global__ __launch_bounds__(TPB, 5) void col_pass(const float* __restrict__ pred,
                                                   const float* __restrict__ gt,
                                                   const float* __restrict__ ratioL,
                                                   float* __restrict__ ratioR,
                                                   float* __restrict__ satr,
                                                   float c) {
    __shared__ v2f Sx[NH], Sy[NH], Sz[NH], Sw[NH];
    const int b = blockIdx.x >> 7;
    const int base = (blockIdx.x & 127) * 16;
    const int tid = threadIdx.x, wave = tid >> 6, lane = tid & 63;
    const float* Pb = pred + (size_t)b * NPTS * 3;
    STAGE_CW(Pb, ratioL + b * NPTS);
    __syncthreads();
    const int own0 = base + wave * 4;
    const float* g0 = gt + ((size_t)b * NPTS + own0) * 3;
    float cx[4], cy[4], cz[4], cb[4];          // c folded into the dot form
    v2f a[4];
    #pragma unroll
    for (int r = 0; r < 4; ++r) {
        float gx = g0[r * 3], gy = g0[r * 3 + 1], gz = g0[r * 3 + 2];
        cx[r] = -2.0f * c * gx; cy[r] = -2.0f * c * gy; cz[r] = -2.0f * c * gz;
        cb[r] = c * (gx * gx + gy * gy + gz * gz);
        a[r] = v2(0.0f);
    }
    for (int i = lane; i < NH; i += 64) {
        v2f px = Sx[i], py = Sy[i], pz = Sz[i], rl = Sw[i];
        v2f cp2 = vfma(px, px, vfma(py, py, pz * pz)) * v2(c);
        #pragma unroll
        for (int r = 0; r < 4; ++r) {
            v2f arg = vfma(v2(cx[r]), px, vfma(v2(cy[r]), py,
                      vfma(v2(cz[r]), pz, cp2 + v2(cb[r]))));
            arg = __builtin_elementwise_min(arg, v2(0.0f));   // c<0: d2>=0
            a[r] = vfma(vexp2(arg), rl, a[r]);
        }
    }
    float as[4];
    #pragma unroll
    for (int r = 0; r < 4; ++r) as[r] = a[r].x + a[r].y;
    #pragma unroll
    for (int o = 1; o < 64; o <<= 1) {
        #pragma unroll
        for (int r = 0; r < 4; ++r) as[r] += __shfl_xor(as[r], o);
    }
    if (lane < 4) {
        const int idx = b * NPTS + own0 + lane;
        const float A = SEL4(as, lane);
        const float sr = FIRST ? 1.0f : satr[idx];
        const float ss = fmaf(sr, A, EPS_F);
        const float rr = sr * fminf(sr / ss, 1.0f);
        ratioR[idx] = rr;
        satr[idx] = fmaxf(fmaf(-rr, A, sr), 0.0f);
    }
}

// Last level (exp == 1): A is column-independent = sum_n ratioL[n].
__global__ __launch_bounds__(256) void col_last(const float* __restrict__ ratioL,
                                                float* __restrict__ ratioR,
                                                const float* __restrict__ satr) {
    __shared__ float part[256];
    const int b = blockIdx.x;
    float acc = 0.0f;
    for (int i = threadIdx.x; i < NPTS; i += 256) acc += ratioL[b * NPTS + i];
    part[threadIdx.x] = acc;
    __syncthreads();
    for (int s = 128; s > 0; s >>= 1) {
        if (threadIdx.x < s) part[threadIdx.x] += part[threadIdx.x + s];
        __syncthreads();
    }
    const float sumRL = part[0];
    for (int m = threadIdx.x; m < NPTS; m += 256) {
        const int idx = b * NPTS + m;
        const float sr = satr[idx];
        const float ss = fmaf(sr, sumRL, EPS_F);
        ratioR[idx] = sr * fminf(sr / ss, 1.0f);
    }
}

// MODE 0 (j<=8): e2 = exp2(cq*d2), e1 = (e2^2)^2; an += e2*satr  (cq = c/4)
// MODE 1 (j==9): e1 = exp2(c*d2); next level 0 -> an_all = sum satr
// MODE 2 (j==10): e1 = 1; cost only.   FIRST: satl = 1.
template <int MODE, bool FIRST>
__global__ __launch_bounds__(TPB, 5) void row_finish(const float* __restrict__ pred,
                                                     const float* __restrict__ gt,
                                                     float* __restrict__ satl,
                                                     float* __restrict__ ratioL,
                                                     const float* __restrict__ ratioR,
                                                     const float* __restrict__ satr,
                                                     float* __restrict__ costAcc,
                                                     float c1, float cq) {
    __shared__ v2f Sx[NH], Sy[NH], Sz[NH], Sw[NH];   // 32768 B
    const int b = blockIdx.x >> 7;
    const int base = (blockIdx.x & 127) * 16;
    const int tid = threadIdx.x, wave = tid >> 6, lane = tid & 63;
    const float* Gb = gt + (size_t)b * NPTS * 3;
    STAGE_CW(Gb, ratioR + b * NPTS);
    __syncthreads();
    const int own0 = base + wave * 4;
    const float* p0 = pred + ((size_t)b * NPTS + own0) * 3;
    const float2* nrp = (const float2*)(satr + b * NPTS);   // L1/L2-hot
    float nx[4], ny[4], nz[4], p2[4];
    v2f s1[4], s2[4], an[4], anall = v2(0.0f);
    #pragma unroll
    for (int r = 0; r < 4; ++r) {
        float px = p0[r * 3], py = p0[r * 3 + 1], pz = p0[r * 3 + 2];
        nx[r] = -2.0f * px; ny[r] = -2.0f * py; nz[r] = -2.0f * pz;
        p2[r] = px * px + py * py + pz * pz;
        s1[r] = v2(0.0f); s2[r] = v2(0.0f); an[r] = v2(0.0f);
    }
    for (int i = lane; i < NH; i += 64) {
        v2f gx = Sx[i], gy = Sy[i], gz = Sz[i], rr = Sw[i];
        v2f g2 = vfma(gx, gx, vfma(gy, gy, gz * gz));
        v2f nr;
        if (MODE <= 1) { float2 q = nrp[i]; nr = (v2f){q.x, q.y}; }
        #pragma unroll
        for (int r = 0; r < 4; ++r) {
            v2f d2 = vmax0(vfma(v2(nx[r]), gx, vfma(v2(ny[r]), gy,
                           vfma(v2(nz[r]), gz, g2 + v2(p2[r])))));
            if (MODE == 0) {
                v2f e2 = vexp2(d2 * v2(cq));
                v2f e22 = e2 * e2;
                an[r] = vfma(e2, nr, an[r]);
                v2f t_ = (e22 * e22) * rr;
                s1[r] += t_;
                s2[r] = vfma(t_, vsqrt(d2), s2[r]);
            } else if (MODE == 1) {
                v2f t_ = vexp2(d2 * v2(c1)) * rr;
                s1[r] += t_;
                s2[r] = vfma(t_, vsqrt(d2), s2[r]);
            } else {
                s2[r] = vfma(rr, vsqrt(d2), s2[r]);
            }
        }
        if (MODE == 1) anall += nr;
    }
    float S1[4], S2[4], AN[4], ana = anall.x + anall.y;
    #pragma unroll
    for (int r = 0; r < 4; ++r) {
        S1[r] = s1[r].x + s1[r].y;
        S2[r] = s2[r].x + s2[r].y;
        AN[r] = an[r].x + an[r].y;
    }
    #pragma unroll
    for (int o = 1; o < 64; o <<= 1) {
        #pragma unroll
        for (int r = 0; r < 4; ++r) {
            S2[r] += __shfl_xor(S2[r], o);
            if (MODE <= 1) S1[r] += __shfl_xor(S1[r], o);
            if (MODE == 0) AN[r] += __shfl_xor(AN[r], o);
        }
        if (MODE == 1) ana += __shfl_xor(ana, o);
    }
    float contrib = 0.0f;
    if (lane < 4) {
        const int idx = b * NPTS + own0 + lane;
        const float rl = ratioL[idx];
        contrib = rl * SEL4(S2, lane);
        if (MODE <= 1) {
            const float sl = FIRST ? 1.0f : satl[idx];
            const float nsl = fmaxf(fmaf(-rl, SEL4(S1, lane), sl), 0.0f);
            satl[idx] = nsl;
            const float den = (MODE == 0) ? SEL4(AN, lane) : ana;
            ratioL[idx] = nsl / (den + EPS_F);
        }
    }
    contrib += __shfl_xor(contrib, 1);
    contrib += __shfl_xor(contrib, 2);       // lanes 0..3 now hold wave total
    __syncthreads();                          // staging reads done; reuse LDS
    float* scr = (float*)Sx;
    if (lane == 0) scr[wave] = contrib;
    __syncthreads();
    if (tid == 0)
        atomicAdd(costAcc, scr[0] + scr[1] + scr[2] + scr[3]);
}

__global__ void finalize(const float* __restrict__ costAcc, float* __restrict__ out) {
    out[0] = costAcc[0] * (1.0f / (float)NPTS);   // radius = 1
}

extern "C" void kernel_launch(void* const* d_in, const int* in_sizes, int n_in,
                              void* d_out, int out_size, void* d_ws, size_t ws_size,
                              hipStream_t stream) {
    const float* pred = (const float*)d_in[0];
    const float* gt   = (const float*)d_in[1];
    float* out = (float*)d_out;

    float* wsf    = (float*)d_ws;
    float* satl   = wsf;
    float* satr   = wsf + NB * NPTS;
    float* ratioL = wsf + 2 * NB * NPTS;
    float* ratioR = wsf + 3 * NB * NPTS;
    float* costAcc = wsf + 4 * NB * NPTS;

    // c[j] = level_j * log2(e); c[j+1] = c[j]/4 exactly for j<=8
    const double LOG2E = 1.4426950408889634;
    float c[11];
    for (int k = 0; k < 10; ++k) c[k] = (float)(-pow(4.0, (double)(8 - k)) * LOG2E);
    c[10] = 0.0f;

    const int blocks = NB * (NPTS / 16);   // 2048 blocks, 5 resident/CU

    row_start<<<blocks, TPB, 0, stream>>>(pred, gt, ratioL, costAcc, c[0]);
    col_pass<true><<<blocks, TPB, 0, stream>>>(pred, gt, ratioL, ratioR, satr, c[0]);
    row_finish<0, true><<<blocks, TPB, 0, stream>>>(pred, gt, satl, ratioL, ratioR, satr,
                                                    costAcc, c[0], c[1]);
    for (int j = 1; j <= 8; ++j) {
        col_pass<false><<<blocks, TPB, 0, stream>>>(pred, gt, ratioL, ratioR, satr, c[j]);
        row_finish<0, false><<<blocks, TPB, 0, stream>>>(pred, gt, satl, ratioL, ratioR,
                                                         satr, costAcc, c[j], c[j + 1]);
    }
    col_pass<false><<<blocks, TPB, 0, stream>>>(pred, gt, ratioL, ratioR, satr, c[9]);
    row_finish<1, false><<<blocks, TPB, 0, stream>>>(pred, gt, satl, ratioL, ratioR, satr,
                                                     costAcc, c[9], 0.0f);
    col_last<<<NB, 256, 0, stream>>>(ratioL, ratioR, satr);
    row_finish<2, false><<<blocks, TPB, 0, stream>>>(pred, gt, satl, ratioL, ratioR, satr,
                                                     costAcc, 0.0f, 0.0f);
    finalize<<<1, 1, 0, stream>>>(costAcc, out);
}